// Round 6
// baseline (559.966 us; speedup 1.0000x reference)
//
#include <hip/hip_runtime.h>

// Problem constants
#define HDIM 64
#define LSEQ 2048
#define BATCH 16
#define LN_EPS 1e-5f
#define D_EPS 1e-6f
#define CHUNK 16
#define NCHUNK 128   // 2048 solve slots (incl. 1 zero-padded) / 16
#define NSEG 16
#define CPS 8        // chunks per segment

typedef unsigned short u16;
typedef unsigned int   u32;

__device__ __forceinline__ float bf2f(u16 v) {
    return __uint_as_float(((u32)v) << 16);
}
__device__ __forceinline__ u16 f2bf(float f) {   // round-to-nearest-even
    u32 u = __float_as_uint(f);
    return (u16)((u + 0x7FFFu + ((u >> 16) & 1u)) >> 16);
}

// ---------------------------------------------------------------------------
// Kernel 1: preprocessing, lane = token (R4 structure, bf16 output).
// h = LayerNorm(e + MLP(e)) computed entirely in-lane; weight addresses are
// wave-uniform -> scalar loads (s_load) feeding v_fma v,s,v. No LDS, no
// cross-lane ops. invd = 1/(h_bf16.h_bf16 + D_EPS) from the ROUNDED h.
// ---------------------------------------------------------------------------
__global__ __launch_bounds__(256, 1) void preprocess_kernel(
    const int* __restrict__ seq, const float* __restrict__ embed,
    const float* __restrict__ W1, const float* __restrict__ b1,
    const float* __restrict__ W2, const float* __restrict__ b2,
    const float* __restrict__ gamma, const float* __restrict__ beta,
    u16* __restrict__ h_out, float* __restrict__ invd_out)
{
    const int tok = blockIdx.x * 256 + threadIdx.x;
    const int v = seq[tok];

    float e[64];
    {
        const float4* ep = (const float4*)(embed + v * HDIM);
#pragma unroll
        for (int i = 0; i < 16; ++i) {
            float4 t = ep[i];
            e[4*i+0] = t.x; e[4*i+1] = t.y; e[4*i+2] = t.z; e[4*i+3] = t.w;
        }
    }

    float ff[64];
#pragma unroll
    for (int c = 0; c < 64; ++c) ff[c] = b2[c];

    for (int j0 = 0; j0 < 128; j0 += 8) {   // 16 iterations, body ~1 KFMA
        float h8[8];
#pragma unroll
        for (int jj = 0; jj < 8; ++jj) h8[jj] = b1[j0 + jj];
#pragma unroll
        for (int i = 0; i < 64; ++i) {
            const float ei = e[i];
#pragma unroll
            for (int jj = 0; jj < 8; ++jj)
                h8[jj] = fmaf(ei, W1[i * 128 + j0 + jj], h8[jj]);
        }
#pragma unroll
        for (int jj = 0; jj < 8; ++jj) {
            const float hv = fmaxf(h8[jj], 0.f);
#pragma unroll
            for (int c = 0; c < 64; ++c)
                ff[c] = fmaf(hv, W2[(j0 + jj) * 64 + c], ff[c]);
        }
    }

    // x = e + ff (into e); LN stats in-lane with 4 accumulators
    float s0=0.f,s1=0.f,s2=0.f,s3=0.f, q0=0.f,q1=0.f,q2=0.f,q3=0.f;
#pragma unroll
    for (int i = 0; i < 64; i += 4) {
        e[i+0] += ff[i+0]; e[i+1] += ff[i+1]; e[i+2] += ff[i+2]; e[i+3] += ff[i+3];
        s0 += e[i+0]; s1 += e[i+1]; s2 += e[i+2]; s3 += e[i+3];
        q0 = fmaf(e[i+0], e[i+0], q0); q1 = fmaf(e[i+1], e[i+1], q1);
        q2 = fmaf(e[i+2], e[i+2], q2); q3 = fmaf(e[i+3], e[i+3], q3);
    }
    const float mu   = ((s0+s1)+(s2+s3)) * (1.0f/64.0f);
    const float var  = ((q0+q1)+(q2+q3)) * (1.0f/64.0f) - mu * mu;
    const float rstd = 1.0f / sqrtf(var + LN_EPS);

    // normalize, round to bf16, accumulate h.h over ROUNDED values, store
    float hh = 0.f;
    uint4* hp = (uint4*)(h_out + (size_t)tok * HDIM);
#pragma unroll
    for (int g = 0; g < 8; ++g) {         // 8 dims per group -> one uint4
        u32 pw[4];
#pragma unroll
        for (int p = 0; p < 4; ++p) {
            const int i = g * 8 + p * 2;
            const float o0 = (e[i+0] - mu) * rstd * gamma[i+0] + beta[i+0];
            const float o1 = (e[i+1] - mu) * rstd * gamma[i+1] + beta[i+1];
            const u16 r0 = f2bf(o0), r1 = f2bf(o1);
            const float q0f = bf2f(r0), q1f = bf2f(r1);
            hh = fmaf(q0f, q0f, hh);
            hh = fmaf(q1f, q1f, hh);
            pw[p] = (u32)r0 | ((u32)r1 << 16);
        }
        hp[g] = make_uint4(pw[0], pw[1], pw[2], pw[3]);
    }
    invd_out[tok] = 1.0f / (hh + D_EPS);
}

// ---------------------------------------------------------------------------
// Kernel 2: segment composition (unchanged from round 5 — controlled).
// Block = (batch b, segment s); maintains in LDS the dense affine action of
// the segment's 8 chunks:
//   S = A_c7 ... A_c0   (64x64),   V = sum_c U_c * (A_{c-1}...A_c0)
// where per chunk (solve order, k_sigma = h[2047-sigma], sigma=0 padded 0):
//   L B = K  (L unit-lower, L[i][j] = (k_i.k_j)*ivd_j),  Z = B S
//   A_c S = S - K^T (D Z),  U_c S = K^T Z
// Writes packed bf16 (S,V) per (b,s) for the tiny serial final kernel.
// ---------------------------------------------------------------------------
__global__ __launch_bounds__(256, 1) void compose_kernel(
    const u16* __restrict__ hb16, const float* __restrict__ invd,
    u32* __restrict__ PK)
{
    const int b = blockIdx.x >> 4;
    const int s = blockIdx.x & 15;
    const u16*   hbase = hb16 + (size_t)b * LSEQ * HDIM;
    const float* dbase = invd + b * LSEQ;

    __shared__ float S[64][68];
    __shared__ float V[64][68];
    __shared__ float K[16][68];
    __shared__ float Bm[16][68];
    __shared__ float Z[16][68];
    __shared__ float Zt[16][68];
    __shared__ float Gm[16][17];
    __shared__ float ivd_s[16];

    const int t = threadIdx.x;

    // init S = I, V = 0
    for (int idx = t; idx < 64 * 64; idx += 256) {
        const int m = idx >> 6, n = idx & 63;
        S[m][n] = (m == n) ? 1.0f : 0.0f;
        V[m][n] = 0.0f;
    }

    for (int cc = 0; cc < CPS; ++cc) {
        const int c = s * CPS + cc;
        __syncthreads();   // staging vs previous phase-5 reads / init

        // ---- stage K (bf16 -> f32) and ivd ----
        {
            const int j  = t >> 4;
            const int n0 = (t & 15) * 4;
            const int sigma = 16 * c + j;
            float4 kv = make_float4(0.f, 0.f, 0.f, 0.f);
            if (sigma > 0) {
                const ushort4 raw = *(const ushort4*)(hbase + (size_t)(2047 - sigma) * HDIM + n0);
                kv.x = bf2f(raw.x); kv.y = bf2f(raw.y); kv.z = bf2f(raw.z); kv.w = bf2f(raw.w);
            }
            *(float4*)&K[j][n0] = kv;
            if (t < 16) ivd_s[t] = dbase[2047 - (16 * c + t)];
        }
        __syncthreads();

        // ---- Gram: Gm[i][j] = (k_i . k_j) * ivd_j, i > j ----
        {
            const int i = t >> 4, j = t & 15;
            if (i > j) {
                float acc = 0.f;
#pragma unroll
                for (int m = 0; m < 64; m += 4) {
                    const float4 a  = *(const float4*)&K[i][m];
                    const float4 bb = *(const float4*)&K[j][m];
                    acc += a.x * bb.x + a.y * bb.y + a.z * bb.z + a.w * bb.w;
                }
                Gm[i][j] = acc * ivd_s[j];
            }
        }
        __syncthreads();

        // ---- B: forward substitution L B = K (wave 0, B rows in registers) --
        if (t < 64) {
            const int n = t;
            float Breg[16];
#pragma unroll
            for (int i = 0; i < 16; ++i) {
                float acc = K[i][n];
#pragma unroll
                for (int j = 0; j < 16; ++j)
                    if (j < i) acc = fmaf(-Gm[i][j], Breg[j], acc);
                Breg[i] = acc;
                Bm[i][n] = acc;
            }
        }
        __syncthreads();

        // ---- Z = B S ; Zt = D Z ----  thread = (i = t&15, col-quad nb = t>>4)
        {
            const int i  = t & 15;
            const int n0 = (t >> 4) * 4;
            float4 z = make_float4(0.f, 0.f, 0.f, 0.f);
#pragma unroll
            for (int mq = 0; mq < 16; ++mq) {
                const float4 bq = *(const float4*)&Bm[i][mq * 4];
                const float4 s0 = *(const float4*)&S[mq * 4 + 0][n0];
                const float4 s1 = *(const float4*)&S[mq * 4 + 1][n0];
                const float4 s2 = *(const float4*)&S[mq * 4 + 2][n0];
                const float4 s3 = *(const float4*)&S[mq * 4 + 3][n0];
                z.x = fmaf(bq.x, s0.x, fmaf(bq.y, s1.x, fmaf(bq.z, s2.x, fmaf(bq.w, s3.x, z.x))));
                z.y = fmaf(bq.x, s0.y, fmaf(bq.y, s1.y, fmaf(bq.z, s2.y, fmaf(bq.w, s3.y, z.y))));
                z.z = fmaf(bq.x, s0.z, fmaf(bq.y, s1.z, fmaf(bq.z, s2.z, fmaf(bq.w, s3.z, z.z))));
                z.w = fmaf(bq.x, s0.w, fmaf(bq.y, s1.w, fmaf(bq.z, s2.w, fmaf(bq.w, s3.w, z.w))));
            }
            *(float4*)&Z[i][n0] = z;
            const float iv = ivd_s[i];
            float4 zt; zt.x = z.x * iv; zt.y = z.y * iv; zt.z = z.z * iv; zt.w = z.w * iv;
            *(float4*)&Zt[i][n0] = zt;
        }
        __syncthreads();

        // ---- S -= K^T Zt ; V += K^T Z ----
        // thread = (nb = t&15 -> n0, mh = t>>4 -> rows mh+16p)
        {
            const int n0 = (t & 15) * 4;
            const int mh = t >> 4;
            float4 sacc[4], vacc[4];
#pragma unroll
            for (int p = 0; p < 4; ++p) {
                sacc[p] = *(float4*)&S[mh + 16 * p][n0];
                vacc[p] = *(float4*)&V[mh + 16 * p][n0];
            }
#pragma unroll
            for (int j = 0; j < 16; ++j) {
                const float4 zq  = *(const float4*)&Z[j][n0];
                const float4 ztq = *(const float4*)&Zt[j][n0];
                const float k0 = K[j][mh];
                const float k1 = K[j][mh + 16];
                const float k2 = K[j][mh + 32];
                const float k3 = K[j][mh + 48];
                vacc[0].x = fmaf(k0, zq.x, vacc[0].x); vacc[0].y = fmaf(k0, zq.y, vacc[0].y);
                vacc[0].z = fmaf(k0, zq.z, vacc[0].z); vacc[0].w = fmaf(k0, zq.w, vacc[0].w);
                vacc[1].x = fmaf(k1, zq.x, vacc[1].x); vacc[1].y = fmaf(k1, zq.y, vacc[1].y);
                vacc[1].z = fmaf(k1, zq.z, vacc[1].z); vacc[1].w = fmaf(k1, zq.w, vacc[1].w);
                vacc[2].x = fmaf(k2, zq.x, vacc[2].x); vacc[2].y = fmaf(k2, zq.y, vacc[2].y);
                vacc[2].z = fmaf(k2, zq.z, vacc[2].z); vacc[2].w = fmaf(k2, zq.w, vacc[2].w);
                vacc[3].x = fmaf(k3, zq.x, vacc[3].x); vacc[3].y = fmaf(k3, zq.y, vacc[3].y);
                vacc[3].z = fmaf(k3, zq.z, vacc[3].z); vacc[3].w = fmaf(k3, zq.w, vacc[3].w);
                sacc[0].x = fmaf(-k0, ztq.x, sacc[0].x); sacc[0].y = fmaf(-k0, ztq.y, sacc[0].y);
                sacc[0].z = fmaf(-k0, ztq.z, sacc[0].z); sacc[0].w = fmaf(-k0, ztq.w, sacc[0].w);
                sacc[1].x = fmaf(-k1, ztq.x, sacc[1].x); sacc[1].y = fmaf(-k1, ztq.y, sacc[1].y);
                sacc[1].z = fmaf(-k1, ztq.z, sacc[1].z); sacc[1].w = fmaf(-k1, ztq.w, sacc[1].w);
                sacc[2].x = fmaf(-k2, ztq.x, sacc[2].x); sacc[2].y = fmaf(-k2, ztq.y, sacc[2].y);
                sacc[2].z = fmaf(-k2, ztq.z, sacc[2].z); sacc[2].w = fmaf(-k2, ztq.w, sacc[2].w);
                sacc[3].x = fmaf(-k3, ztq.x, sacc[3].x); sacc[3].y = fmaf(-k3, ztq.y, sacc[3].y);
                sacc[3].z = fmaf(-k3, ztq.z, sacc[3].z); sacc[3].w = fmaf(-k3, ztq.w, sacc[3].w);
            }
#pragma unroll
            for (int p = 0; p < 4; ++p) {
                *(float4*)&S[mh + 16 * p][n0] = sacc[p];
                *(float4*)&V[mh + 16 * p][n0] = vacc[p];
            }
        }
    }
    __syncthreads();

    // ---- writeback: pk[j*64+i] = pack(bf16(S[i][j]), bf16(V[i][j])) ----
    u32* pk = PK + ((size_t)(b * NSEG + s) << 12);
    for (int idx = t; idx < 4096; idx += 256) {
        const int j = idx >> 6, i = idx & 63;
        const u32 sb = ((u32)f2bf(S[i][j])) << 16;
        const u32 vb = (u32)f2bf(V[i][j]);
        pk[idx] = sb | vb;
    }
}

// ---------------------------------------------------------------------------
// Kernel 3: serial segment pass + output projection (unchanged from round 5).
//   r = q; for s: ctx += V_s r; r = S_s r;   out = (ctx Wr + br) Wo + bo
// ---------------------------------------------------------------------------
__global__ __launch_bounds__(64, 1) void final_kernel(
    const u16* __restrict__ hb16, const u32* __restrict__ PK,
    const float* __restrict__ Wr, const float* __restrict__ br,
    const float* __restrict__ Wo, const float* __restrict__ bo,
    float* __restrict__ out)
{
    const int b    = blockIdx.x;
    const int lane = threadIdx.x;

    __shared__ float rl[64];
    __shared__ float cs[64], rs[64];

    float r   = bf2f(hb16[(size_t)b * LSEQ * HDIM + (size_t)2047 * HDIM + lane]);
    float ctx = 0.f;

    for (int s = 0; s < NSEG; ++s) {
        rl[lane] = r;
        __syncthreads();
        const u32* pk = PK + ((size_t)(b * NSEG + s) << 12);
        float accr = 0.f, accc = 0.f;
#pragma unroll 8
        for (int j = 0; j < 64; ++j) {
            const u32 p = pk[j * 64 + lane];
            const float Sv = __uint_as_float(p & 0xFFFF0000u);
            const float Vv = __uint_as_float(p << 16);
            const float rj = rl[j];
            accr = fmaf(Sv, rj, accr);
            accc = fmaf(Vv, rj, accc);
        }
        ctx += accc;
        r = accr;
        __syncthreads();
    }

    cs[lane] = ctx;
    __syncthreads();
    float rv = br[lane];
#pragma unroll
    for (int i = 0; i < 64; ++i) rv = fmaf(cs[i], Wr[i * HDIM + lane], rv);
    rs[lane] = rv;
    __syncthreads();
    float ov = bo[lane];
#pragma unroll
    for (int i = 0; i < 64; ++i) ov = fmaf(rs[i], Wo[i * HDIM + lane], ov);
    out[(size_t)b * HDIM + lane] = ov;
}

// ---------------------------------------------------------------------------
extern "C" void kernel_launch(void* const* d_in, const int* in_sizes, int n_in,
                              void* d_out, int out_size, void* d_ws, size_t ws_size,
                              hipStream_t stream)
{
    const int*   seq   = (const int*)  d_in[0];
    const float* embed = (const float*)d_in[1];
    const float* W1    = (const float*)d_in[2];
    const float* b1    = (const float*)d_in[3];
    const float* W2    = (const float*)d_in[4];
    const float* b2    = (const float*)d_in[5];
    const float* gamma = (const float*)d_in[6];
    const float* beta  = (const float*)d_in[7];
    const float* Wr    = (const float*)d_in[8];
    const float* br    = (const float*)d_in[9];
    const float* Wo    = (const float*)d_in[10];
    const float* bo    = (const float*)d_in[11];

    u16*   h_ws    = (u16*)d_ws;                                   // 4 MB
    float* invd_ws = (float*)(h_ws + (size_t)BATCH * LSEQ * HDIM); // 128 KB
    u32*   pk_ws   = (u32*)(invd_ws + (size_t)BATCH * LSEQ);       // 4 MB
    float* outp    = (float*)d_out;

    hipLaunchKernelGGL(preprocess_kernel, dim3(BATCH * LSEQ / 256), dim3(256), 0, stream,
                       seq, embed, W1, b1, W2, b2, gamma, beta, h_ws, invd_ws);
    hipLaunchKernelGGL(compose_kernel, dim3(BATCH * NSEG), dim3(256), 0, stream,
                       h_ws, invd_ws, pk_ws);
    hipLaunchKernelGGL(final_kernel, dim3(BATCH), dim3(64), 0, stream,
                       h_ws, pk_ws, Wr, br, Wo, bo, outp);
}

// Round 7
// 175.687 us; speedup vs baseline: 3.1873x; 3.1873x over previous
//
#include <hip/hip_runtime.h>

// Problem constants
#define HDIM 64
#define LSEQ 2048
#define BATCH 16
#define LN_EPS 1e-5f
#define D_EPS 1e-6f
#define CHUNK 16
#define NCHUNK 128   // 2048 solve slots (incl. 1 zero-padded) / 16
#define NSEG 16
#define CPS 8        // chunks per segment

typedef unsigned short u16;
typedef unsigned int   u32;

__device__ __forceinline__ float bf2f(u16 v) {
    return __uint_as_float(((u32)v) << 16);
}
__device__ __forceinline__ u16 f2bf(float f) {   // round-to-nearest-even
    u32 u = __float_as_uint(f);
    return (u16)((u + 0x7FFFu + ((u >> 16) & 1u)) >> 16);
}

// ---------------------------------------------------------------------------
// Kernel 1: preprocessing as a register-blocked tiled GEMM. 64 tokens/block,
// 512 blocks, 256 threads. W1/W2 staged once per block; e staged transposed
// (eT[dim][tok]) so every hot read in the MLP loops is a conflict-free
// ds_read_b128 feeding 16-32 FMAs (vs R5's one ds_read_b32 per FMA operand).
//   MLP1 microtile: 4 tok x (4+4 outs, column-quad-cyclic: 4c and 64+4c)
//   MLP2 microtile: 4 tok x 4 outs
// LN + bf16 rounding + invd (from ROUNDED h) fused at the end.
// ---------------------------------------------------------------------------
__global__ __launch_bounds__(256, 1) void preprocess_kernel(
    const int* __restrict__ seq, const float* __restrict__ embed,
    const float* __restrict__ W1, const float* __restrict__ b1,
    const float* __restrict__ W2, const float* __restrict__ b2,
    const float* __restrict__ gamma, const float* __restrict__ beta,
    u16* __restrict__ h_out, float* __restrict__ invd_out)
{
    __shared__ float sW1[64 * 132];    // [k][out], stride 132 (33 float4)
    __shared__ float sW2[128 * 68];    // [k][out], stride 68
    __shared__ float eT[64 * 68];      // [dim][tok] -> becomes x = e+ff in place
    __shared__ float hidT[128 * 68];   // [hid][tok], relu'd MLP1 output
    __shared__ float red1[4][66], red2[4][66];
    __shared__ float smu[66], srstd[66];

    const int t    = threadIdx.x;
    const int tok0 = blockIdx.x * 64;

    // ---- stage W1 (64x128) and W2 (128x64) ----
    {
        const float4* s1 = (const float4*)W1;   // 2048 float4
#pragma unroll
        for (int q = 0; q < 8; ++q) {
            const int m = t + 256 * q;
            const int row = m >> 5, col = m & 31;
            *(float4*)&sW1[row * 132 + col * 4] = s1[m];
        }
        const float4* s2 = (const float4*)W2;   // 2048 float4
#pragma unroll
        for (int q = 0; q < 8; ++q) {
            const int m = t + 256 * q;
            const int row = m >> 4, col = m & 15;
            *(float4*)&sW2[row * 68 + col * 4] = s2[m];
        }
    }
    // ---- stage embeddings transposed: thread (tk = t>>2, p = t&3) ----
    {
        const int tk = t >> 2, p = t & 3;
        const int v = seq[tok0 + tk];
        const float* er = embed + v * HDIM + 16 * p;
#pragma unroll
        for (int q = 0; q < 4; ++q) {
            const float4 ev = *(const float4*)(er + 4 * q);
            const int d = 16 * p + 4 * q;
            eT[(d + 0) * 68 + tk] = ev.x;
            eT[(d + 1) * 68 + tk] = ev.y;
            eT[(d + 2) * 68 + tk] = ev.z;
            eT[(d + 3) * 68 + tk] = ev.w;
        }
    }
    __syncthreads();

    const int r = t >> 4;   // token quad: toks 4r..4r+3
    const int c = t & 15;   // out quad

    // ---- MLP1: hid = relu(e W1 + b1); outs {4c..4c+3} and {64+4c..64+4c+3}
    {
        float acc0[4][4], acc1[4][4];
#pragma unroll
        for (int o = 0; o < 4; ++o) {
            const float bA = b1[4 * c + o];
            const float bB = b1[64 + 4 * c + o];
#pragma unroll
            for (int j = 0; j < 4; ++j) { acc0[j][o] = bA; acc1[j][o] = bB; }
        }
        for (int k = 0; k < 64; ++k) {
            const float4 ev = *(const float4*)&eT[k * 68 + 4 * r];
            const float4 wa = *(const float4*)&sW1[k * 132 + 4 * c];
            const float4 wb = *(const float4*)&sW1[k * 132 + 64 + 4 * c];
            const float e4[4] = {ev.x, ev.y, ev.z, ev.w};
            const float a4[4] = {wa.x, wa.y, wa.z, wa.w};
            const float b4[4] = {wb.x, wb.y, wb.z, wb.w};
#pragma unroll
            for (int j = 0; j < 4; ++j)
#pragma unroll
                for (int o = 0; o < 4; ++o) {
                    acc0[j][o] = fmaf(e4[j], a4[o], acc0[j][o]);
                    acc1[j][o] = fmaf(e4[j], b4[o], acc1[j][o]);
                }
        }
#pragma unroll
        for (int o = 0; o < 4; ++o)
#pragma unroll
            for (int j = 0; j < 4; ++j) {
                hidT[(4 * c + o) * 68 + 4 * r + j]      = fmaxf(acc0[j][o], 0.f);
                hidT[(64 + 4 * c + o) * 68 + 4 * r + j] = fmaxf(acc1[j][o], 0.f);
            }
    }
    __syncthreads();

    // ---- MLP2: ff = hid W2 + b2; then x = e + ff in place into eT ----
    {
        float acc[4][4];
#pragma unroll
        for (int o = 0; o < 4; ++o) {
            const float bv = b2[4 * c + o];
#pragma unroll
            for (int j = 0; j < 4; ++j) acc[j][o] = bv;
        }
        for (int k = 0; k < 128; ++k) {
            const float4 hv = *(const float4*)&hidT[k * 68 + 4 * r];
            const float4 wv = *(const float4*)&sW2[k * 68 + 4 * c];
            const float h4[4] = {hv.x, hv.y, hv.z, hv.w};
            const float w4[4] = {wv.x, wv.y, wv.z, wv.w};
#pragma unroll
            for (int j = 0; j < 4; ++j)
#pragma unroll
                for (int o = 0; o < 4; ++o)
                    acc[j][o] = fmaf(h4[j], w4[o], acc[j][o]);
        }
#pragma unroll
        for (int o = 0; o < 4; ++o)
#pragma unroll
            for (int j = 0; j < 4; ++j)
                eT[(4 * c + o) * 68 + (4 * r + j)] += acc[j][o];
    }
    __syncthreads();

    // ---- LN stats: thread (tk = t&63, p = t>>6) sums 16 dims ----
    {
        const int tk = t & 63, p = t >> 6;
        float s = 0.f, q = 0.f;
#pragma unroll
        for (int i = 0; i < 16; ++i) {
            const float x = eT[(16 * p + i) * 68 + tk];
            s += x;
            q = fmaf(x, x, q);
        }
        red1[p][tk] = s;
        red2[p][tk] = q;
    }
    __syncthreads();
    if (t < 64) {
        const float s  = ((red1[0][t] + red1[1][t]) + (red1[2][t] + red1[3][t]));
        const float qq = ((red2[0][t] + red2[1][t]) + (red2[2][t] + red2[3][t]));
        const float mu  = s * (1.0f / 64.0f);
        const float var = qq * (1.0f / 64.0f) - mu * mu;
        smu[t]   = mu;
        srstd[t] = 1.0f / sqrtf(var + LN_EPS);
    }
    __syncthreads();

    // ---- normalize, round bf16, write h; hh over ROUNDED values ----
    {
        const int tk = t >> 2, p = t & 3;
        const float mu = smu[tk], rstd = srstd[tk];
        float hh = 0.f;
        u32 pw[8];
#pragma unroll
        for (int i2 = 0; i2 < 8; ++i2) {
            const int d = 16 * p + 2 * i2;
            const float x0 = eT[(d + 0) * 68 + tk];
            const float x1 = eT[(d + 1) * 68 + tk];
            const float o0 = (x0 - mu) * rstd * gamma[d + 0] + beta[d + 0];
            const float o1 = (x1 - mu) * rstd * gamma[d + 1] + beta[d + 1];
            const u16 r0 = f2bf(o0), r1 = f2bf(o1);
            const float q0f = bf2f(r0), q1f = bf2f(r1);
            hh = fmaf(q0f, q0f, hh);
            hh = fmaf(q1f, q1f, hh);
            pw[i2] = (u32)r0 | ((u32)r1 << 16);
        }
        uint4* hp = (uint4*)(h_out + (size_t)(tok0 + tk) * HDIM + 16 * p);
        hp[0] = make_uint4(pw[0], pw[1], pw[2], pw[3]);
        hp[1] = make_uint4(pw[4], pw[5], pw[6], pw[7]);
        red1[p][tk] = hh;
    }
    __syncthreads();
    if (t < 64) {
        const float hh = ((red1[0][t] + red1[1][t]) + (red1[2][t] + red1[3][t]));
        invd_out[tok0 + t] = 1.0f / (hh + D_EPS);
    }
}

// ---------------------------------------------------------------------------
// Kernel 2: segment composition (unchanged from round 5 — controlled).
// Block = (batch b, segment s); maintains in LDS the dense affine action of
// the segment's 8 chunks:
//   S = A_c7 ... A_c0   (64x64),   V = sum_c U_c * (A_{c-1}...A_c0)
// where per chunk (solve order, k_sigma = h[2047-sigma], sigma=0 padded 0):
//   L B = K  (L unit-lower, L[i][j] = (k_i.k_j)*ivd_j),  Z = B S
//   A_c S = S - K^T (D Z),  U_c S = K^T Z
// Writes packed bf16 (S,V) per (b,s) for the tiny serial final kernel.
// ---------------------------------------------------------------------------
__global__ __launch_bounds__(256, 1) void compose_kernel(
    const u16* __restrict__ hb16, const float* __restrict__ invd,
    u32* __restrict__ PK)
{
    const int b = blockIdx.x >> 4;
    const int s = blockIdx.x & 15;
    const u16*   hbase = hb16 + (size_t)b * LSEQ * HDIM;
    const float* dbase = invd + b * LSEQ;

    __shared__ float S[64][68];
    __shared__ float V[64][68];
    __shared__ float K[16][68];
    __shared__ float Bm[16][68];
    __shared__ float Z[16][68];
    __shared__ float Zt[16][68];
    __shared__ float Gm[16][17];
    __shared__ float ivd_s[16];

    const int t = threadIdx.x;

    // init S = I, V = 0
    for (int idx = t; idx < 64 * 64; idx += 256) {
        const int m = idx >> 6, n = idx & 63;
        S[m][n] = (m == n) ? 1.0f : 0.0f;
        V[m][n] = 0.0f;
    }

    for (int cc = 0; cc < CPS; ++cc) {
        const int c = s * CPS + cc;
        __syncthreads();   // staging vs previous phase-5 reads / init

        // ---- stage K (bf16 -> f32) and ivd ----
        {
            const int j  = t >> 4;
            const int n0 = (t & 15) * 4;
            const int sigma = 16 * c + j;
            float4 kv = make_float4(0.f, 0.f, 0.f, 0.f);
            if (sigma > 0) {
                const ushort4 raw = *(const ushort4*)(hbase + (size_t)(2047 - sigma) * HDIM + n0);
                kv.x = bf2f(raw.x); kv.y = bf2f(raw.y); kv.z = bf2f(raw.z); kv.w = bf2f(raw.w);
            }
            *(float4*)&K[j][n0] = kv;
            if (t < 16) ivd_s[t] = dbase[2047 - (16 * c + t)];
        }
        __syncthreads();

        // ---- Gram: Gm[i][j] = (k_i . k_j) * ivd_j, i > j ----
        {
            const int i = t >> 4, j = t & 15;
            if (i > j) {
                float acc = 0.f;
#pragma unroll
                for (int m = 0; m < 64; m += 4) {
                    const float4 a  = *(const float4*)&K[i][m];
                    const float4 bb = *(const float4*)&K[j][m];
                    acc += a.x * bb.x + a.y * bb.y + a.z * bb.z + a.w * bb.w;
                }
                Gm[i][j] = acc * ivd_s[j];
            }
        }
        __syncthreads();

        // ---- B: forward substitution L B = K (wave 0, B rows in registers) --
        if (t < 64) {
            const int n = t;
            float Breg[16];
#pragma unroll
            for (int i = 0; i < 16; ++i) {
                float acc = K[i][n];
#pragma unroll
                for (int j = 0; j < 16; ++j)
                    if (j < i) acc = fmaf(-Gm[i][j], Breg[j], acc);
                Breg[i] = acc;
                Bm[i][n] = acc;
            }
        }
        __syncthreads();

        // ---- Z = B S ; Zt = D Z ----  thread = (i = t&15, col-quad nb = t>>4)
        {
            const int i  = t & 15;
            const int n0 = (t >> 4) * 4;
            float4 z = make_float4(0.f, 0.f, 0.f, 0.f);
#pragma unroll
            for (int mq = 0; mq < 16; ++mq) {
                const float4 bq = *(const float4*)&Bm[i][mq * 4];
                const float4 s0 = *(const float4*)&S[mq * 4 + 0][n0];
                const float4 s1 = *(const float4*)&S[mq * 4 + 1][n0];
                const float4 s2 = *(const float4*)&S[mq * 4 + 2][n0];
                const float4 s3 = *(const float4*)&S[mq * 4 + 3][n0];
                z.x = fmaf(bq.x, s0.x, fmaf(bq.y, s1.x, fmaf(bq.z, s2.x, fmaf(bq.w, s3.x, z.x))));
                z.y = fmaf(bq.x, s0.y, fmaf(bq.y, s1.y, fmaf(bq.z, s2.y, fmaf(bq.w, s3.y, z.y))));
                z.z = fmaf(bq.x, s0.z, fmaf(bq.y, s1.z, fmaf(bq.z, s2.z, fmaf(bq.w, s3.z, z.z))));
                z.w = fmaf(bq.x, s0.w, fmaf(bq.y, s1.w, fmaf(bq.z, s2.w, fmaf(bq.w, s3.w, z.w))));
            }
            *(float4*)&Z[i][n0] = z;
            const float iv = ivd_s[i];
            float4 zt; zt.x = z.x * iv; zt.y = z.y * iv; zt.z = z.z * iv; zt.w = z.w * iv;
            *(float4*)&Zt[i][n0] = zt;
        }
        __syncthreads();

        // ---- S -= K^T Zt ; V += K^T Z ----
        // thread = (nb = t&15 -> n0, mh = t>>4 -> rows mh+16p)
        {
            const int n0 = (t & 15) * 4;
            const int mh = t >> 4;
            float4 sacc[4], vacc[4];
#pragma unroll
            for (int p = 0; p < 4; ++p) {
                sacc[p] = *(float4*)&S[mh + 16 * p][n0];
                vacc[p] = *(float4*)&V[mh + 16 * p][n0];
            }
#pragma unroll
            for (int j = 0; j < 16; ++j) {
                const float4 zq  = *(const float4*)&Z[j][n0];
                const float4 ztq = *(const float4*)&Zt[j][n0];
                const float k0 = K[j][mh];
                const float k1 = K[j][mh + 16];
                const float k2 = K[j][mh + 32];
                const float k3 = K[j][mh + 48];
                vacc[0].x = fmaf(k0, zq.x, vacc[0].x); vacc[0].y = fmaf(k0, zq.y, vacc[0].y);
                vacc[0].z = fmaf(k0, zq.z, vacc[0].z); vacc[0].w = fmaf(k0, zq.w, vacc[0].w);
                vacc[1].x = fmaf(k1, zq.x, vacc[1].x); vacc[1].y = fmaf(k1, zq.y, vacc[1].y);
                vacc[1].z = fmaf(k1, zq.z, vacc[1].z); vacc[1].w = fmaf(k1, zq.w, vacc[1].w);
                vacc[2].x = fmaf(k2, zq.x, vacc[2].x); vacc[2].y = fmaf(k2, zq.y, vacc[2].y);
                vacc[2].z = fmaf(k2, zq.z, vacc[2].z); vacc[2].w = fmaf(k2, zq.w, vacc[2].w);
                vacc[3].x = fmaf(k3, zq.x, vacc[3].x); vacc[3].y = fmaf(k3, zq.y, vacc[3].y);
                vacc[3].z = fmaf(k3, zq.z, vacc[3].z); vacc[3].w = fmaf(k3, zq.w, vacc[3].w);
                sacc[0].x = fmaf(-k0, ztq.x, sacc[0].x); sacc[0].y = fmaf(-k0, ztq.y, sacc[0].y);
                sacc[0].z = fmaf(-k0, ztq.z, sacc[0].z); sacc[0].w = fmaf(-k0, ztq.w, sacc[0].w);
                sacc[1].x = fmaf(-k1, ztq.x, sacc[1].x); sacc[1].y = fmaf(-k1, ztq.y, sacc[1].y);
                sacc[1].z = fmaf(-k1, ztq.z, sacc[1].z); sacc[1].w = fmaf(-k1, ztq.w, sacc[1].w);
                sacc[2].x = fmaf(-k2, ztq.x, sacc[2].x); sacc[2].y = fmaf(-k2, ztq.y, sacc[2].y);
                sacc[2].z = fmaf(-k2, ztq.z, sacc[2].z); sacc[2].w = fmaf(-k2, ztq.w, sacc[2].w);
                sacc[3].x = fmaf(-k3, ztq.x, sacc[3].x); sacc[3].y = fmaf(-k3, ztq.y, sacc[3].y);
                sacc[3].z = fmaf(-k3, ztq.z, sacc[3].z); sacc[3].w = fmaf(-k3, ztq.w, sacc[3].w);
            }
#pragma unroll
            for (int p = 0; p < 4; ++p) {
                *(float4*)&S[mh + 16 * p][n0] = sacc[p];
                *(float4*)&V[mh + 16 * p][n0] = vacc[p];
            }
        }
    }
    __syncthreads();

    // ---- writeback: pk[j*64+i] = pack(bf16(S[i][j]), bf16(V[i][j])) ----
    u32* pk = PK + ((size_t)(b * NSEG + s) << 12);
    for (int idx = t; idx < 4096; idx += 256) {
        const int j = idx >> 6, i = idx & 63;
        const u32 sb = ((u32)f2bf(S[i][j])) << 16;
        const u32 vb = (u32)f2bf(V[i][j]);
        pk[idx] = sb | vb;
    }
}

// ---------------------------------------------------------------------------
// Kernel 3: serial segment pass + output projection (unchanged from round 5).
//   r = q; for s: ctx += V_s r; r = S_s r;   out = (ctx Wr + br) Wo + bo
// ---------------------------------------------------------------------------
__global__ __launch_bounds__(64, 1) void final_kernel(
    const u16* __restrict__ hb16, const u32* __restrict__ PK,
    const float* __restrict__ Wr, const float* __restrict__ br,
    const float* __restrict__ Wo, const float* __restrict__ bo,
    float* __restrict__ out)
{
    const int b    = blockIdx.x;
    const int lane = threadIdx.x;

    __shared__ float rl[64];
    __shared__ float cs[64], rs[64];

    float r   = bf2f(hb16[(size_t)b * LSEQ * HDIM + (size_t)2047 * HDIM + lane]);
    float ctx = 0.f;

    for (int s = 0; s < NSEG; ++s) {
        rl[lane] = r;
        __syncthreads();
        const u32* pk = PK + ((size_t)(b * NSEG + s) << 12);
        float accr = 0.f, accc = 0.f;
#pragma unroll 8
        for (int j = 0; j < 64; ++j) {
            const u32 p = pk[j * 64 + lane];
            const float Sv = __uint_as_float(p & 0xFFFF0000u);
            const float Vv = __uint_as_float(p << 16);
            const float rj = rl[j];
            accr = fmaf(Sv, rj, accr);
            accc = fmaf(Vv, rj, accc);
        }
        ctx += accc;
        r = accr;
        __syncthreads();
    }

    cs[lane] = ctx;
    __syncthreads();
    float rv = br[lane];
#pragma unroll
    for (int i = 0; i < 64; ++i) rv = fmaf(cs[i], Wr[i * HDIM + lane], rv);
    rs[lane] = rv;
    __syncthreads();
    float ov = bo[lane];
#pragma unroll
    for (int i = 0; i < 64; ++i) ov = fmaf(rs[i], Wo[i * HDIM + lane], ov);
    out[(size_t)b * HDIM + lane] = ov;
}

// ---------------------------------------------------------------------------
extern "C" void kernel_launch(void* const* d_in, const int* in_sizes, int n_in,
                              void* d_out, int out_size, void* d_ws, size_t ws_size,
                              hipStream_t stream)
{
    const int*   seq   = (const int*)  d_in[0];
    const float* embed = (const float*)d_in[1];
    const float* W1    = (const float*)d_in[2];
    const float* b1    = (const float*)d_in[3];
    const float* W2    = (const float*)d_in[4];
    const float* b2    = (const float*)d_in[5];
    const float* gamma = (const float*)d_in[6];
    const float* beta  = (const float*)d_in[7];
    const float* Wr    = (const float*)d_in[8];
    const float* br    = (const float*)d_in[9];
    const float* Wo    = (const float*)d_in[10];
    const float* bo    = (const float*)d_in[11];

    u16*   h_ws    = (u16*)d_ws;                                   // 4 MB
    float* invd_ws = (float*)(h_ws + (size_t)BATCH * LSEQ * HDIM); // 128 KB
    u32*   pk_ws   = (u32*)(invd_ws + (size_t)BATCH * LSEQ);       // 4 MB
    float* outp    = (float*)d_out;

    hipLaunchKernelGGL(preprocess_kernel, dim3(BATCH * LSEQ / 64), dim3(256), 0, stream,
                       seq, embed, W1, b1, W2, b2, gamma, beta, h_ws, invd_ws);
    hipLaunchKernelGGL(compose_kernel, dim3(BATCH * NSEG), dim3(256), 0, stream,
                       h_ws, invd_ws, pk_ws);
    hipLaunchKernelGGL(final_kernel, dim3(BATCH), dim3(64), 0, stream,
                       h_ws, pk_ws, Wr, br, Wo, bo, outp);
}

// Round 8
// 144.356 us; speedup vs baseline: 3.8791x; 1.2170x over previous
//
#include <hip/hip_runtime.h>

// Problem constants
#define HDIM 64
#define LSEQ 2048
#define BATCH 16
#define LN_EPS 1e-5f
#define D_EPS 1e-6f
#define CHUNK 16
#define NCHUNK 128   // 2048 solve slots (incl. 1 zero-padded) / 16
#define NSEG 16
#define CPS 8        // chunks per segment

typedef unsigned short u16;
typedef unsigned int   u32;

__device__ __forceinline__ float bf2f(u16 v) {
    return __uint_as_float(((u32)v) << 16);
}
__device__ __forceinline__ u16 f2bf(float f) {   // round-to-nearest-even
    u32 u = __float_as_uint(f);
    return (u16)((u + 0x7FFFu + ((u >> 16) & 1u)) >> 16);
}

// ---------------------------------------------------------------------------
// Kernel 1: preprocessing as a register-blocked tiled GEMM (unchanged from
// round 7 — controlled). 64 tokens/block, 512 blocks, 256 threads.
// ---------------------------------------------------------------------------
__global__ __launch_bounds__(256, 1) void preprocess_kernel(
    const int* __restrict__ seq, const float* __restrict__ embed,
    const float* __restrict__ W1, const float* __restrict__ b1,
    const float* __restrict__ W2, const float* __restrict__ b2,
    const float* __restrict__ gamma, const float* __restrict__ beta,
    u16* __restrict__ h_out, float* __restrict__ invd_out)
{
    __shared__ float sW1[64 * 132];    // [k][out], stride 132 (33 float4)
    __shared__ float sW2[128 * 68];    // [k][out], stride 68
    __shared__ float eT[64 * 68];      // [dim][tok] -> becomes x = e+ff in place
    __shared__ float hidT[128 * 68];   // [hid][tok], relu'd MLP1 output
    __shared__ float red1[4][66], red2[4][66];
    __shared__ float smu[66], srstd[66];

    const int t    = threadIdx.x;
    const int tok0 = blockIdx.x * 64;

    // ---- stage W1 (64x128) and W2 (128x64) ----
    {
        const float4* s1 = (const float4*)W1;   // 2048 float4
#pragma unroll
        for (int q = 0; q < 8; ++q) {
            const int m = t + 256 * q;
            const int row = m >> 5, col = m & 31;
            *(float4*)&sW1[row * 132 + col * 4] = s1[m];
        }
        const float4* s2 = (const float4*)W2;   // 2048 float4
#pragma unroll
        for (int q = 0; q < 8; ++q) {
            const int m = t + 256 * q;
            const int row = m >> 4, col = m & 15;
            *(float4*)&sW2[row * 68 + col * 4] = s2[m];
        }
    }
    // ---- stage embeddings transposed: thread (tk = t>>2, p = t&3) ----
    {
        const int tk = t >> 2, p = t & 3;
        const int v = seq[tok0 + tk];
        const float* er = embed + v * HDIM + 16 * p;
#pragma unroll
        for (int q = 0; q < 4; ++q) {
            const float4 ev = *(const float4*)(er + 4 * q);
            const int d = 16 * p + 4 * q;
            eT[(d + 0) * 68 + tk] = ev.x;
            eT[(d + 1) * 68 + tk] = ev.y;
            eT[(d + 2) * 68 + tk] = ev.z;
            eT[(d + 3) * 68 + tk] = ev.w;
        }
    }
    __syncthreads();

    const int r = t >> 4;   // token quad: toks 4r..4r+3
    const int c = t & 15;   // out quad

    // ---- MLP1: hid = relu(e W1 + b1); outs {4c..4c+3} and {64+4c..64+4c+3}
    {
        float acc0[4][4], acc1[4][4];
#pragma unroll
        for (int o = 0; o < 4; ++o) {
            const float bA = b1[4 * c + o];
            const float bB = b1[64 + 4 * c + o];
#pragma unroll
            for (int j = 0; j < 4; ++j) { acc0[j][o] = bA; acc1[j][o] = bB; }
        }
        for (int k = 0; k < 64; ++k) {
            const float4 ev = *(const float4*)&eT[k * 68 + 4 * r];
            const float4 wa = *(const float4*)&sW1[k * 132 + 4 * c];
            const float4 wb = *(const float4*)&sW1[k * 132 + 64 + 4 * c];
            const float e4[4] = {ev.x, ev.y, ev.z, ev.w};
            const float a4[4] = {wa.x, wa.y, wa.z, wa.w};
            const float b4[4] = {wb.x, wb.y, wb.z, wb.w};
#pragma unroll
            for (int j = 0; j < 4; ++j)
#pragma unroll
                for (int o = 0; o < 4; ++o) {
                    acc0[j][o] = fmaf(e4[j], a4[o], acc0[j][o]);
                    acc1[j][o] = fmaf(e4[j], b4[o], acc1[j][o]);
                }
        }
#pragma unroll
        for (int o = 0; o < 4; ++o)
#pragma unroll
            for (int j = 0; j < 4; ++j) {
                hidT[(4 * c + o) * 68 + 4 * r + j]      = fmaxf(acc0[j][o], 0.f);
                hidT[(64 + 4 * c + o) * 68 + 4 * r + j] = fmaxf(acc1[j][o], 0.f);
            }
    }
    __syncthreads();

    // ---- MLP2: ff = hid W2 + b2; then x = e + ff in place into eT ----
    {
        float acc[4][4];
#pragma unroll
        for (int o = 0; o < 4; ++o) {
            const float bv = b2[4 * c + o];
#pragma unroll
            for (int j = 0; j < 4; ++j) acc[j][o] = bv;
        }
        for (int k = 0; k < 128; ++k) {
            const float4 hv = *(const float4*)&hidT[k * 68 + 4 * r];
            const float4 wv = *(const float4*)&sW2[k * 68 + 4 * c];
            const float h4[4] = {hv.x, hv.y, hv.z, hv.w};
            const float w4[4] = {wv.x, wv.y, wv.z, wv.w};
#pragma unroll
            for (int j = 0; j < 4; ++j)
#pragma unroll
                for (int o = 0; o < 4; ++o)
                    acc[j][o] = fmaf(h4[j], w4[o], acc[j][o]);
        }
#pragma unroll
        for (int o = 0; o < 4; ++o)
#pragma unroll
            for (int j = 0; j < 4; ++j)
                eT[(4 * c + o) * 68 + (4 * r + j)] += acc[j][o];
    }
    __syncthreads();

    // ---- LN stats: thread (tk = t&63, p = t>>6) sums 16 dims ----
    {
        const int tk = t & 63, p = t >> 6;
        float s = 0.f, q = 0.f;
#pragma unroll
        for (int i = 0; i < 16; ++i) {
            const float x = eT[(16 * p + i) * 68 + tk];
            s += x;
            q = fmaf(x, x, q);
        }
        red1[p][tk] = s;
        red2[p][tk] = q;
    }
    __syncthreads();
    if (t < 64) {
        const float s  = ((red1[0][t] + red1[1][t]) + (red1[2][t] + red1[3][t]));
        const float qq = ((red2[0][t] + red2[1][t]) + (red2[2][t] + red2[3][t]));
        const float mu  = s * (1.0f / 64.0f);
        const float var = qq * (1.0f / 64.0f) - mu * mu;
        smu[t]   = mu;
        srstd[t] = 1.0f / sqrtf(var + LN_EPS);
    }
    __syncthreads();

    // ---- normalize, round bf16, write h; hh over ROUNDED values ----
    {
        const int tk = t >> 2, p = t & 3;
        const float mu = smu[tk], rstd = srstd[tk];
        float hh = 0.f;
        u32 pw[8];
#pragma unroll
        for (int i2 = 0; i2 < 8; ++i2) {
            const int d = 16 * p + 2 * i2;
            const float x0 = eT[(d + 0) * 68 + tk];
            const float x1 = eT[(d + 1) * 68 + tk];
            const float o0 = (x0 - mu) * rstd * gamma[d + 0] + beta[d + 0];
            const float o1 = (x1 - mu) * rstd * gamma[d + 1] + beta[d + 1];
            const u16 r0 = f2bf(o0), r1 = f2bf(o1);
            const float q0f = bf2f(r0), q1f = bf2f(r1);
            hh = fmaf(q0f, q0f, hh);
            hh = fmaf(q1f, q1f, hh);
            pw[i2] = (u32)r0 | ((u32)r1 << 16);
        }
        uint4* hp = (uint4*)(h_out + (size_t)(tok0 + tk) * HDIM + 16 * p);
        hp[0] = make_uint4(pw[0], pw[1], pw[2], pw[3]);
        hp[1] = make_uint4(pw[4], pw[5], pw[6], pw[7]);
        red1[p][tk] = hh;
    }
    __syncthreads();
    if (t < 64) {
        const float hh = ((red1[0][t] + red1[1][t]) + (red1[2][t] + red1[3][t]));
        invd_out[tok0 + t] = 1.0f / (hh + D_EPS);
    }
}

// ---------------------------------------------------------------------------
// Kernel 2: segment composition (unchanged from round 5 — controlled).
// ---------------------------------------------------------------------------
__global__ __launch_bounds__(256, 1) void compose_kernel(
    const u16* __restrict__ hb16, const float* __restrict__ invd,
    u32* __restrict__ PK)
{
    const int b = blockIdx.x >> 4;
    const int s = blockIdx.x & 15;
    const u16*   hbase = hb16 + (size_t)b * LSEQ * HDIM;
    const float* dbase = invd + b * LSEQ;

    __shared__ float S[64][68];
    __shared__ float V[64][68];
    __shared__ float K[16][68];
    __shared__ float Bm[16][68];
    __shared__ float Z[16][68];
    __shared__ float Zt[16][68];
    __shared__ float Gm[16][17];
    __shared__ float ivd_s[16];

    const int t = threadIdx.x;

    // init S = I, V = 0
    for (int idx = t; idx < 64 * 64; idx += 256) {
        const int m = idx >> 6, n = idx & 63;
        S[m][n] = (m == n) ? 1.0f : 0.0f;
        V[m][n] = 0.0f;
    }

    for (int cc = 0; cc < CPS; ++cc) {
        const int c = s * CPS + cc;
        __syncthreads();   // staging vs previous phase-5 reads / init

        // ---- stage K (bf16 -> f32) and ivd ----
        {
            const int j  = t >> 4;
            const int n0 = (t & 15) * 4;
            const int sigma = 16 * c + j;
            float4 kv = make_float4(0.f, 0.f, 0.f, 0.f);
            if (sigma > 0) {
                const ushort4 raw = *(const ushort4*)(hbase + (size_t)(2047 - sigma) * HDIM + n0);
                kv.x = bf2f(raw.x); kv.y = bf2f(raw.y); kv.z = bf2f(raw.z); kv.w = bf2f(raw.w);
            }
            *(float4*)&K[j][n0] = kv;
            if (t < 16) ivd_s[t] = dbase[2047 - (16 * c + t)];
        }
        __syncthreads();

        // ---- Gram: Gm[i][j] = (k_i . k_j) * ivd_j, i > j ----
        {
            const int i = t >> 4, j = t & 15;
            if (i > j) {
                float acc = 0.f;
#pragma unroll
                for (int m = 0; m < 64; m += 4) {
                    const float4 a  = *(const float4*)&K[i][m];
                    const float4 bb = *(const float4*)&K[j][m];
                    acc += a.x * bb.x + a.y * bb.y + a.z * bb.z + a.w * bb.w;
                }
                Gm[i][j] = acc * ivd_s[j];
            }
        }
        __syncthreads();

        // ---- B: forward substitution L B = K (wave 0, B rows in registers) --
        if (t < 64) {
            const int n = t;
            float Breg[16];
#pragma unroll
            for (int i = 0; i < 16; ++i) {
                float acc = K[i][n];
#pragma unroll
                for (int j = 0; j < 16; ++j)
                    if (j < i) acc = fmaf(-Gm[i][j], Breg[j], acc);
                Breg[i] = acc;
                Bm[i][n] = acc;
            }
        }
        __syncthreads();

        // ---- Z = B S ; Zt = D Z ----  thread = (i = t&15, col-quad nb = t>>4)
        {
            const int i  = t & 15;
            const int n0 = (t >> 4) * 4;
            float4 z = make_float4(0.f, 0.f, 0.f, 0.f);
#pragma unroll
            for (int mq = 0; mq < 16; ++mq) {
                const float4 bq = *(const float4*)&Bm[i][mq * 4];
                const float4 s0 = *(const float4*)&S[mq * 4 + 0][n0];
                const float4 s1 = *(const float4*)&S[mq * 4 + 1][n0];
                const float4 s2 = *(const float4*)&S[mq * 4 + 2][n0];
                const float4 s3 = *(const float4*)&S[mq * 4 + 3][n0];
                z.x = fmaf(bq.x, s0.x, fmaf(bq.y, s1.x, fmaf(bq.z, s2.x, fmaf(bq.w, s3.x, z.x))));
                z.y = fmaf(bq.x, s0.y, fmaf(bq.y, s1.y, fmaf(bq.z, s2.y, fmaf(bq.w, s3.y, z.y))));
                z.z = fmaf(bq.x, s0.z, fmaf(bq.y, s1.z, fmaf(bq.z, s2.z, fmaf(bq.w, s3.z, z.z))));
                z.w = fmaf(bq.x, s0.w, fmaf(bq.y, s1.w, fmaf(bq.z, s2.w, fmaf(bq.w, s3.w, z.w))));
            }
            *(float4*)&Z[i][n0] = z;
            const float iv = ivd_s[i];
            float4 zt; zt.x = z.x * iv; zt.y = z.y * iv; zt.z = z.z * iv; zt.w = z.w * iv;
            *(float4*)&Zt[i][n0] = zt;
        }
        __syncthreads();

        // ---- S -= K^T Zt ; V += K^T Z ----
        {
            const int n0 = (t & 15) * 4;
            const int mh = t >> 4;
            float4 sacc[4], vacc[4];
#pragma unroll
            for (int p = 0; p < 4; ++p) {
                sacc[p] = *(float4*)&S[mh + 16 * p][n0];
                vacc[p] = *(float4*)&V[mh + 16 * p][n0];
            }
#pragma unroll
            for (int j = 0; j < 16; ++j) {
                const float4 zq  = *(const float4*)&Z[j][n0];
                const float4 ztq = *(const float4*)&Zt[j][n0];
                const float k0 = K[j][mh];
                const float k1 = K[j][mh + 16];
                const float k2 = K[j][mh + 32];
                const float k3 = K[j][mh + 48];
                vacc[0].x = fmaf(k0, zq.x, vacc[0].x); vacc[0].y = fmaf(k0, zq.y, vacc[0].y);
                vacc[0].z = fmaf(k0, zq.z, vacc[0].z); vacc[0].w = fmaf(k0, zq.w, vacc[0].w);
                vacc[1].x = fmaf(k1, zq.x, vacc[1].x); vacc[1].y = fmaf(k1, zq.y, vacc[1].y);
                vacc[1].z = fmaf(k1, zq.z, vacc[1].z); vacc[1].w = fmaf(k1, zq.w, vacc[1].w);
                vacc[2].x = fmaf(k2, zq.x, vacc[2].x); vacc[2].y = fmaf(k2, zq.y, vacc[2].y);
                vacc[2].z = fmaf(k2, zq.z, vacc[2].z); vacc[2].w = fmaf(k2, zq.w, vacc[2].w);
                vacc[3].x = fmaf(k3, zq.x, vacc[3].x); vacc[3].y = fmaf(k3, zq.y, vacc[3].y);
                vacc[3].z = fmaf(k3, zq.z, vacc[3].z); vacc[3].w = fmaf(k3, zq.w, vacc[3].w);
                sacc[0].x = fmaf(-k0, ztq.x, sacc[0].x); sacc[0].y = fmaf(-k0, ztq.y, sacc[0].y);
                sacc[0].z = fmaf(-k0, ztq.z, sacc[0].z); sacc[0].w = fmaf(-k0, ztq.w, sacc[0].w);
                sacc[1].x = fmaf(-k1, ztq.x, sacc[1].x); sacc[1].y = fmaf(-k1, ztq.y, sacc[1].y);
                sacc[1].z = fmaf(-k1, ztq.z, sacc[1].z); sacc[1].w = fmaf(-k1, ztq.w, sacc[1].w);
                sacc[2].x = fmaf(-k2, ztq.x, sacc[2].x); sacc[2].y = fmaf(-k2, ztq.y, sacc[2].y);
                sacc[2].z = fmaf(-k2, ztq.z, sacc[2].z); sacc[2].w = fmaf(-k2, ztq.w, sacc[2].w);
                sacc[3].x = fmaf(-k3, ztq.x, sacc[3].x); sacc[3].y = fmaf(-k3, ztq.y, sacc[3].y);
                sacc[3].z = fmaf(-k3, ztq.z, sacc[3].z); sacc[3].w = fmaf(-k3, ztq.w, sacc[3].w);
            }
#pragma unroll
            for (int p = 0; p < 4; ++p) {
                *(float4*)&S[mh + 16 * p][n0] = sacc[p];
                *(float4*)&V[mh + 16 * p][n0] = vacc[p];
            }
        }
    }
    __syncthreads();

    // ---- writeback: pk[j*64+i] = pack(bf16(S[i][j]), bf16(V[i][j])) ----
    u32* pk = PK + ((size_t)(b * NSEG + s) << 12);
    for (int idx = t; idx < 4096; idx += 256) {
        const int j = idx >> 6, i = idx & 63;
        const u32 sb = ((u32)f2bf(S[i][j])) << 16;
        const u32 vb = (u32)f2bf(V[i][j]);
        pk[idx] = sb | vb;
    }
}

// ---------------------------------------------------------------------------
// Kernel 3: serial segment pass + output projection — REWORKED.
// 16 blocks x 256 threads (4 waves/batch). Wave p owns j-range [16p,16p+16):
// per segment each lane loads 16 PK words (vs 64), with the NEXT segment's
// loads issued before the current segment's math (addresses are r-independent)
// so the L2/L3 latency overlaps the reduce chain. Cross-wave reduce via LDS
// partials; every wave redundantly computes and writes the full r (identical
// values -> own-wave visibility suffices for correctness).
// ---------------------------------------------------------------------------
__global__ __launch_bounds__(256, 1) void final_kernel(
    const u16* __restrict__ hb16, const u32* __restrict__ PK,
    const float* __restrict__ Wr, const float* __restrict__ br,
    const float* __restrict__ Wo, const float* __restrict__ bo,
    float* __restrict__ out)
{
    const int b    = blockIdx.x;
    const int t    = threadIdx.x;
    const int lane = t & 63;
    const int p    = t >> 6;         // wave id = j-slice

    __shared__ float psum[4][72];    // cross-wave partials (padded rows)
    __shared__ float rl[64];
    __shared__ float cs[64], rs[64];

    // r0 = q (every wave writes the same full copy)
    rl[lane] = bf2f(hb16[(size_t)b * LSEQ * HDIM + (size_t)2047 * HDIM + lane]);

    float ctxp = 0.f;                // per-wave ctx partial (j-slice p)

    u32 cur[16], nxt[16];
    {
        const u32* pk0 = PK + ((size_t)(b * NSEG + 0) << 12);
#pragma unroll
        for (int jj = 0; jj < 16; ++jj)
            cur[jj] = pk0[(p * 16 + jj) * 64 + lane];
    }
    __syncthreads();

    for (int s = 0; s < NSEG; ++s) {
        // prefetch segment s+1 (clamped; addresses independent of r)
        const int sn = (s + 1 < NSEG) ? s + 1 : s;
        const u32* pkn = PK + ((size_t)(b * NSEG + sn) << 12);
#pragma unroll
        for (int jj = 0; jj < 16; ++jj)
            nxt[jj] = pkn[(p * 16 + jj) * 64 + lane];

        // partial matvecs over this wave's 16 j's
        float accr = 0.f;
#pragma unroll
        for (int jj = 0; jj < 16; ++jj) {
            const u32 pv = cur[jj];
            const float Sv = __uint_as_float(pv & 0xFFFF0000u);
            const float Vv = __uint_as_float(pv << 16);
            const float rj = rl[p * 16 + jj];
            accr = fmaf(Sv, rj, accr);
            ctxp = fmaf(Vv, rj, ctxp);
        }
        psum[p][lane] = accr;
        __syncthreads();
        const float rn = (psum[0][lane] + psum[1][lane]) + (psum[2][lane] + psum[3][lane]);
        __syncthreads();             // psum reads done before next overwrite
        rl[lane] = rn;               // own-wave write, own-wave read next iter

#pragma unroll
        for (int jj = 0; jj < 16; ++jj) cur[jj] = nxt[jj];
    }

    // ---- reduce ctx partials ----
    psum[p][lane] = ctxp;
    __syncthreads();
    if (t < 64)
        cs[t] = (psum[0][t] + psum[1][t]) + (psum[2][t] + psum[3][t]);
    __syncthreads();

    // ---- out = (ctx Wr + br) Wo + bo, i-dimension split across 4 waves ----
    float rv = (p == 0) ? br[lane] : 0.f;
#pragma unroll
    for (int i = 0; i < 16; ++i)
        rv = fmaf(cs[p * 16 + i], Wr[(p * 16 + i) * HDIM + lane], rv);
    psum[p][lane] = rv;
    __syncthreads();
    if (t < 64)
        rs[t] = (psum[0][t] + psum[1][t]) + (psum[2][t] + psum[3][t]);
    __syncthreads();

    float ov = (p == 0) ? bo[lane] : 0.f;
#pragma unroll
    for (int i = 0; i < 16; ++i)
        ov = fmaf(rs[p * 16 + i], Wo[(p * 16 + i) * HDIM + lane], ov);
    psum[p][lane] = ov;
    __syncthreads();
    if (t < 64)
        out[(size_t)b * HDIM + t] = (psum[0][t] + psum[1][t]) + (psum[2][t] + psum[3][t]);
}

// ---------------------------------------------------------------------------
extern "C" void kernel_launch(void* const* d_in, const int* in_sizes, int n_in,
                              void* d_out, int out_size, void* d_ws, size_t ws_size,
                              hipStream_t stream)
{
    const int*   seq   = (const int*)  d_in[0];
    const float* embed = (const float*)d_in[1];
    const float* W1    = (const float*)d_in[2];
    const float* b1    = (const float*)d_in[3];
    const float* W2    = (const float*)d_in[4];
    const float* b2    = (const float*)d_in[5];
    const float* gamma = (const float*)d_in[6];
    const float* beta  = (const float*)d_in[7];
    const float* Wr    = (const float*)d_in[8];
    const float* br    = (const float*)d_in[9];
    const float* Wo    = (const float*)d_in[10];
    const float* bo    = (const float*)d_in[11];

    u16*   h_ws    = (u16*)d_ws;                                   // 4 MB
    float* invd_ws = (float*)(h_ws + (size_t)BATCH * LSEQ * HDIM); // 128 KB
    u32*   pk_ws   = (u32*)(invd_ws + (size_t)BATCH * LSEQ);       // 4 MB
    float* outp    = (float*)d_out;

    hipLaunchKernelGGL(preprocess_kernel, dim3(BATCH * LSEQ / 64), dim3(256), 0, stream,
                       seq, embed, W1, b1, W2, b2, gamma, beta, h_ws, invd_ws);
    hipLaunchKernelGGL(compose_kernel, dim3(BATCH * NSEG), dim3(256), 0, stream,
                       h_ws, invd_ws, pk_ws);
    hipLaunchKernelGGL(final_kernel, dim3(BATCH), dim3(256), 0, stream,
                       h_ws, pk_ws, Wr, br, Wo, bo, outp);
}